// Round 12
// baseline (2783.162 us; speedup 1.0000x reference)
//
// Persistent clustered RNN for PQMatcher on gfx950.
// 256 blocks = 64 clusters (one per batch) x 4 blocks, 1024 threads each.
// R12: ONE cross-block sync per step.
//  * Ma (91.2KB) now lives in LDS, full copy per block -> every block
//    computes FULL tpre + FULL B/softmax locally. SYNC-1 (s-partials) and
//    its gather/barriers are deleted. gh exchange folds into SYNC-2
//    (produced in P1, consumed in F -- no extra latency).
//  * Uqh moved out of LDS (no room): Phase C reads it from global (read-only,
//    L1/L2-cached, 38KB/step/CU) -- also frees C's ~1800cy of LDS-pipe load.
//  * LDS: dyn 130,112B (Ma 91,200 + Wuq 38,912) + ~14KB static < 160KB.
//  * gh/gi payload step-parity double-buffered (single-sync reuse rule;
//    safety via flag transitivity at step i+1).
//  * Register split unchanged except Ma regs dropped (tpre is LDS-based):
//    Whh on t in [158,384), Wg on [384,984), Wih b-regs on t<900.
// Weights: Whh/Wg/Wih in a/b regs as before; Wuq/Ma in LDS; Uqh in L2.
#include <hip/hip_runtime.h>
#include <hip/hip_fp16.h>

typedef _Float16 h2_t __attribute__((ext_vector_type(2)));

// LDS-only barrier: no vmcnt drain (use ONLY where no cross-wave VMEM dep).
#define BAR_LGKM() \
  asm volatile("s_waitcnt lgkmcnt(0)\n\ts_barrier" ::: "memory")

__device__ __forceinline__ float dot2f(int w, int x, float acc) {
#if __has_builtin(__builtin_amdgcn_fdot2)
  return __builtin_amdgcn_fdot2(__builtin_bit_cast(h2_t, w),
                                __builtin_bit_cast(h2_t, x), acc, false);
#else
  h2_t a = __builtin_bit_cast(h2_t, w);
  h2_t b = __builtin_bit_cast(h2_t, x);
  return acc + (float)a[0] * (float)b[0] + (float)a[1] * (float)b[1];
#endif
}

__device__ __forceinline__ float rcp_f(float x) {
#if __has_builtin(__builtin_amdgcn_rcpf)
  return __builtin_amdgcn_rcpf(x);
#else
  return 1.0f / x;
#endif
}

__device__ __forceinline__ float fast_tanh(float x) {
  float e = exp2f(x * 2.885390082f);
  return 1.0f - 2.0f * rcp_f(e + 1.0f);
}
__device__ __forceinline__ float fast_sigmoid(float x) {
  return rcp_f(1.0f + exp2f(x * -1.442695041f));
}
__device__ __forceinline__ int packh2(float a, float b) {
  h2_t h;
  h[0] = (_Float16)a;
  h[1] = (_Float16)b;
  return __builtin_bit_cast(int, h);
}

// Coherent (agent-scope, relaxed) accessors: no cache-maintenance ops.
__device__ __forceinline__ int ldi_coh(const int* p) {
  return __hip_atomic_load((int*)p, __ATOMIC_RELAXED, __HIP_MEMORY_SCOPE_AGENT);
}
__device__ __forceinline__ float ldf_coh(const float* p) {
  return __hip_atomic_load((float*)p, __ATOMIC_RELAXED,
                           __HIP_MEMORY_SCOPE_AGENT);
}
__device__ __forceinline__ void sti_coh(int* p, int v) {
  __hip_atomic_store(p, v, __ATOMIC_RELAXED, __HIP_MEMORY_SCOPE_AGENT);
}
__device__ __forceinline__ void stf_coh(float* p, float v) {
  __hip_atomic_store(p, v, __ATOMIC_RELAXED, __HIP_MEMORY_SCOPE_AGENT);
}

#define DOTC(W, X, A)                                                          \
  {                                                                            \
    int4 _x = (X);                                                             \
    A = dot2f((W).x, _x.x, A);                                                 \
    A = dot2f((W).y, _x.y, A);                                                 \
    A = dot2f((W).z, _x.z, A);                                                 \
    A = dot2f((W).w, _x.w, A);                                                 \
  }

// ---------------------------------------------------------------------------
// Weight fold/transpose (unchanged layouts) + flag zeroing.
// ---------------------------------------------------------------------------
__global__ void prep_weights(const float* __restrict__ Wp,
                             const float* __restrict__ Wv,
                             const float* __restrict__ Wg,
                             const float* __restrict__ Wih,
                             const float* __restrict__ Whh,
                             __half* __restrict__ oMa, __half* __restrict__ oWg,
                             __half* __restrict__ oWih,
                             __half* __restrict__ oWhh, int* __restrict__ flags,
                             int* __restrict__ payload) {
  if (blockIdx.x == 0) {
    for (int j = threadIdx.x; j < 1024; j += 256) flags[j] = 0;
  }
  int idx = blockIdx.x * 256 + threadIdx.x;
  const int NMa = 150 * 304, NWg = 600 * 304, NWih = 900 * 304,
            NWhh = 452 * 152;
  if (idx < NMa) {
    int r = idx / 304, c = idx % 304;
    float v = 0.f;
    if (c < 150)
      v = Wp[r * 300 + c] + Wp[r * 300 + 150 + c];
    else if (c >= 152 && c < 302)
      v = Wv[r * 150 + (c - 152)];
    oMa[(c >> 3) * 1200 + r * 8 + (c & 7)] = __float2half(v);
    return;
  }
  idx -= NMa;
  if (idx < NWg) {
    int r = idx / 304, c = idx % 304;
    float v = 0.f;
    if (c < 150)
      v = Wg[r * 600 + c] + Wg[r * 600 + 150 + c];
    else if (c >= 152 && c < 302) {
      int d = c - 152;
      v = Wg[r * 600 + 300 + d] + Wg[r * 600 + 450 + d];
    }
    oWg[(c >> 3) * 4800 + r * 8 + (c & 7)] = __float2half(v);
    return;
  }
  idx -= NWg;
  if (idx < NWih) {
    int s = idx / 304, c = idx % 304;
    int r = s >> 1, off = (s & 1) * 300;
    float v = (c < 300) ? Wih[r * 600 + off + c] : 0.f;
    oWih[(c >> 3) * 7200 + s * 8 + (c & 7)] = __float2half(v);
    return;
  }
  idx -= NWih;
  if (idx < NWhh) {
    int r = idx / 152, c = idx % 152;
    float v = (r < 450 && c < 150) ? Whh[r * 150 + c] : 0.f;
    oWhh[(c >> 3) * 3616 + r * 8 + (c & 7)] = __float2half(v);
  }
}

// ---------------------------------------------------------------------------
// Prep 2: Wuq[b][l][h], Uqh[b][l][d]  (unchanged)
// ---------------------------------------------------------------------------
__global__ __launch_bounds__(256) void prep_wuq(const float* __restrict__ Uq,
                                                const float* __restrict__ Wq,
                                                __half* __restrict__ oWuq,
                                                __half* __restrict__ oUqh) {
  __shared__ float sUql[64 * 150];
  const int l = blockIdx.x, tid = threadIdx.x;
  for (int idx = tid; idx < 9600; idx += 256) sUql[idx] = Uq[l * 9600 + idx];
  __syncthreads();
  for (int idx = tid; idx < 64 * 152; idx += 256) {
    int bb = idx / 152, d = idx % 152;
    float v = (d < 150) ? sUql[bb * 150 + d] : 0.f;
    oUqh[(size_t)bb * 19456 + l * 152 + d] = __float2half(v);
  }
  if (tid < 152) {
    const int h = tid;
    if (h < 150) {
      float wq[150];
#pragma unroll
      for (int d = 0; d < 150; ++d)
        wq[d] = Wq[h * 300 + d] + Wq[h * 300 + 150 + d];
      for (int bb = 0; bb < 64; ++bb) {
        float acc = 0.f;
#pragma unroll
        for (int d = 0; d < 150; ++d) acc += wq[d] * sUql[bb * 150 + d];
        oWuq[(size_t)bb * 19456 + l * 152 + h] = __float2half(acc);
      }
    } else {
      for (int bb = 0; bb < 64; ++bb)
        oWuq[(size_t)bb * 19456 + l * 152 + h] = __float2half(0.f);
    }
  }
}

// ---------------------------------------------------------------------------
__global__ __launch_bounds__(1024, 1) void pq_main(
    const float* __restrict__ Up, const float* __restrict__ V,
    const float* __restrict__ v0, const float* __restrict__ b_ih,
    const float* __restrict__ b_hh, const int* __restrict__ gWuq,
    const __half* __restrict__ gUqh, const int* __restrict__ gMa,
    const int* __restrict__ gWg, const int* __restrict__ gWih,
    const int* __restrict__ gWhh, int* __restrict__ flags,
    int* __restrict__ payload, float* __restrict__ out) {
  __shared__ __align__(16) float sTpre[152];
  __shared__ __align__(16) float sV[152];
  __shared__ __align__(16) float sGh[456];
  __shared__ __align__(16) float sS[128];
  __shared__ __align__(16) float sSS[4];
  __shared__ __align__(16) float sC0[152];
  __shared__ __align__(16) float sU[152];
  __shared__ __align__(16) float sv_[152];
  __shared__ __align__(16) int sXd[152];
  __shared__ __align__(16) int svh[76];
  __shared__ __align__(16) int sRgh[304];
  __shared__ __align__(16) float sGi[456];
  __shared__ __align__(16) float sBih[456];
  __shared__ __align__(16) float sBhh[456];
  extern __shared__ __align__(16) int dynlds[];
  int4* lMa4 = (int4*)dynlds;        // 5700 int4 (91,200 B): [chunk][row]
  int* sWuq = dynlds + 22800;        // 9728 ints (38,912 B)

  const int t = threadIdx.x;
  const int c = blockIdx.x & 63;  // cluster == batch
  const int q = blockIdx.x >> 6;  // quarter within cluster
  const int b = c;

  int* myflags = flags + c * 16;
  int* pl = payload + c * 6144;
  float* plGh0 = (float*)pl;             // gh parity 0 [0,456)
  float* plGh1 = (float*)(pl + 512);     // gh parity 1
  float* plGi0 = (float*)(pl + 1024);    // gi partials parity 0: 4 x 456
  float* plGi1 = (float*)(pl + 2848);    // gi partials parity 1

  const int4* MaT4 = (const int4*)gMa;
  const int4* WgT4 = (const int4*)gWg;
  const int4* WihT4 = (const int4*)gWih;
  const int4* WhhT4 = (const int4*)gWhh;

  const int baseR = 113 * q - (q == 3 ? 1 : 0);  // 0,113,226,338
  const int cntR = (q < 2) ? 113 : 112;
  // Wih column-split chunk range for this quarter (packed-halves space)
  const int c_lo = (q == 0) ? 0 : (q == 1) ? 18 : (q == 2) ? 38 : 56;
  const int c_hi = (q == 0) ? 18 : (q == 1) ? 37 : (q == 2) ? 56 : 75;

  // ---- load owned weight chunks into registers (no Ma regs in R12) ----
  int4 a0, a1, a2, a3, a4, a5, a6, a7, a8, a9;
  int4 b0, b1, b2, b3, b4, b5, b6, b7, b8, b9;
  {
    const int4* p;
    int nr, sub, step, nch, row;
    if (t >= 158 && t < 384) {  // Whh rows baseR+rl, 2 lanes/row
      p = WhhT4; nr = 452; step = 2; nch = 19;
      int u2 = t - 158; sub = u2 & 1; row = baseR + (u2 >> 1);
    } else if (t >= 384 && t < 984) {  // Wg rows 150q+rl, 4 lanes/row
      p = WgT4; nr = 600; step = 4; nch = 38;
      int u2 = t - 384; sub = u2 & 3; row = 150 * q + (u2 >> 2);
    } else {  // unused lanes: harmless defined load
      p = WhhT4; nr = 452; step = 2; nch = 19; sub = 0; row = 0;
    }
#define LDA(i)                                                                 \
  {                                                                            \
    int cc = sub + step * (i);                                                 \
    if (cc > nch - 1) cc = nch - 1;                                            \
    a##i = p[cc * nr + row];                                                   \
  }
    LDA(0) LDA(1) LDA(2) LDA(3) LDA(4) LDA(5) LDA(6) LDA(7) LDA(8) LDA(9)
#undef LDA
  }
  {
    // Wih COLUMN split: all 450 rows, chunks c_lo+sub+2k (k<10), 2 lanes/row
    int row = (t < 900) ? (t >> 1) : 0;
    int sub = (t < 900) ? (t & 1) : 0;
#define LDB(i)                                                                 \
  {                                                                            \
    int cq = c_lo + sub + 2 * (i);                                             \
    if (cq > c_hi) cq = c_hi;                                                  \
    int hf = (cq >= 38) ? 1 : 0;                                               \
    int cc = cq - 38 * hf;                                                     \
    b##i = WihT4[cc * 900 + 2 * row + hf];                                     \
  }
    LDB(0) LDB(1) LDB(2) LDB(3) LDB(4) LDB(5) LDB(6) LDB(7) LDB(8) LDB(9)
#undef LDB
  }

  // ---- LDS init: full Ma + Wuq resident; state vectors; biases ----
  for (int idx = t; idx < 5700; idx += 1024) lMa4[idx] = MaT4[idx];
  for (int idx = t; idx < 9728; idx += 1024) sWuq[idx] = gWuq[b * 9728 + idx];
  if (t < 150) {
    sV[t] = V[b * 150 + t];
    float v_ = v0[b * 150 + t];
    sv_[t] = v_;
    float vn = __shfl_down(v_, 1);
    if (!(t & 1)) svh[t >> 1] = packh2(v_, vn);
    float u_ = Up[b * 150 + t];
    sU[t] = u_;
    float un = __shfl_down(u_, 1);
    if (!(t & 1)) sXd[t >> 1] = packh2(u_, un);
  }
  for (int idx = t; idx < 450; idx += 1024) {
    sBih[idx] = b_ih[idx];
    sBhh[idx] = b_hh[idx];
  }
  if (t < 304) sRgh[t] = 0;  // non-owned halves must stay zero (column split)
  if (t < 152) sTpre[t] = 0.f;  // pads 150,151 stay zero forever
  if (t == 0) {
    svh[75] = 0;
    sXd[75] = 0;
    sXd[151] = 0;
    sV[150] = 0.f;
    sV[151] = 0.f;
  }
  const int4* sXd4 = (const int4*)sXd;
  const int4* svh4 = (const int4*)svh;
  const int4* sRgh4 = (const int4*)sRgh;
  __syncthreads();

#pragma unroll 1
  for (int i = 0; i < 128; ++i) {
    float* plGhP = (i & 1) ? plGh1 : plGh0;
    float* plGiP = (i & 1) ? plGi1 : plGi0;
    float unext = 0.f;
    if (t >= 640 && t < 790) {
      int ii = (i < 127) ? (i + 1) : 127;
      unext = Up[ii * 9600 + b * 150 + (t - 640)];
    }

    // ---- Phase 1: FULL tpre from LDS-Ma (t<150, 1 lane/row)
    //      || gh quarter -> payload (t in [158,384))
    if (t < 150) {
      float acc0 = 0.f, acc1 = 0.f;
#pragma unroll
      for (int cc = 0; cc < 38; cc += 2) {
        int4 w0 = lMa4[cc * 150 + t];
        int4 w1 = lMa4[(cc + 1) * 150 + t];
        int4 x0 = (cc < 19) ? sXd4[cc] : svh4[cc - 19];
        int4 x1 = (cc + 1 < 19) ? sXd4[cc + 1] : svh4[cc + 1 - 19];
        DOTC(w0, x0, acc0)
        DOTC(w1, x1, acc1)
      }
      sTpre[t] = acc0 + acc1;
    } else if (t < 384 && t >= 158) {
      int u2 = t - 158;
      int rl = u2 >> 1, sub = u2 & 1;
      int r = baseR + rl;
      float acc0 = 0.f, acc1 = 0.f;
#define HHD(i2, A)                                                             \
  {                                                                            \
    int cc = sub + 2 * (i2);                                                   \
    if (cc < 19) DOTC(a##i2, svh4[cc], A)                                      \
  }
      HHD(0, acc0) HHD(1, acc1) HHD(2, acc0) HHD(3, acc1) HHD(4, acc0)
      HHD(5, acc1) HHD(6, acc0) HHD(7, acc1) HHD(8, acc0) HHD(9, acc1)
#undef HHD
      float acc = acc0 + acc1;
      acc += __shfl_xor(acc, 1);
      if (sub == 0 && rl < cntR) stf_coh(&plGhP[r], acc + sBhh[r]);
    }
    BAR_LGKM();

    // ---- Phase B (FULL, all 1024 threads): s_l over all 76 w-slots
    {
      const int l = t >> 3, sub = t & 7;
      const int base = l * 76;
      float acc = 0.f;
#pragma unroll
      for (int k = 0; k < 10; ++k) {
        int w = sub + 8 * k;
        if (w < 76) {
          int qq = sWuq[base + w];
          float2 tp = ((const float2*)sTpre)[w];
          float2 vv = ((const float2*)sV)[w];
          h2_t hq = __builtin_bit_cast(h2_t, qq);
          acc += fast_tanh((float)hq[0] + tp.x) * vv.x;
          acc += fast_tanh((float)hq[1] + tp.y) * vv.y;
        }
      }
      acc += __shfl_xor(acc, 1);
      acc += __shfl_xor(acc, 2);
      acc += __shfl_xor(acc, 4);
      if (sub == 0) sS[l] = acc;
    }
    BAR_LGKM();

    // ---- exp + denominator (local; no max: |s|<~10, exp2 safe in f32)
    if (t < 128) {
      float e = exp2f(sS[t] * 1.442695041f);
      sS[t] = e;
      float es = e;
#pragma unroll
      for (int o = 1; o < 64; o <<= 1) es += __shfl_xor(es, o);
      if (t == 0) sSS[0] = es;
      if (t == 64) sSS[1] = es;
    }
    BAR_LGKM();

    // ---- Phase C (replicated, Uqh from GLOBAL/L2): c0 via in-wave lq reduce
    if (t < 600) {
      const int d = t >> 2, lq = t & 3;
      const __half* src = gUqh + (size_t)b * 19456 + (size_t)(lq * 32) * 152 + d;
      const float* a = sS + lq * 32;
      float acc = 0.f;
#pragma unroll
      for (int j = 0; j < 32; ++j) {
        acc += a[j] * __half2float(src[j * 152]);
      }
      acc += __shfl_xor(acc, 1);
      acc += __shfl_xor(acc, 2);  // all 4 lanes hold full c0_raw[d]
      float inv = rcp_f(sSS[0] + sSS[1]);
      float c0 = acc * inv;
      float cn = __shfl_down(c0, 4);  // c0[d+1]
      if (lq == 0) {
        sC0[d] = c0;
        if (!(d & 1)) sXd[76 + (d >> 1)] = packh2(c0, cn);
      }
    }
    BAR_LGKM();

    // ---- Phase D: rg quarter (t in [384,984)), full 38 chunks, LOCAL write
    if (t >= 384 && t < 984) {
      int u2 = t - 384;
      int rl = u2 >> 2, sub = u2 & 3;
      int j = 150 * q + rl;
      float acc0 = 0.f, acc1 = 0.f;
#define WGD(i2, A)                                                             \
  {                                                                            \
    int cc = sub + 4 * (i2);                                                   \
    if (cc < 38) DOTC(a##i2, sXd4[cc], A)                                      \
  }
      WGD(0, acc0) WGD(1, acc1) WGD(2, acc0) WGD(3, acc1) WGD(4, acc0)
      WGD(5, acc1) WGD(6, acc0) WGD(7, acc1) WGD(8, acc0) WGD(9, acc1)
#undef WGD
      float acc = acc0 + acc1;
      acc += __shfl_xor(acc, 1);
      acc += __shfl_xor(acc, 2);
      if (sub == 0) {
        float rb;
        if (j < 150)
          rb = sU[j];
        else if (j < 300)
          rb = sU[j - 150];
        else if (j < 450)
          rb = sC0[j - 300];
        else
          rb = sC0[j - 450];
        float rg = rb * fast_sigmoid(acc);
        ((__half*)sRgh)[(j < 300) ? j : (j + 4)] = __float2half(rg);
      }
    }
    BAR_LGKM();

    // ---- Phase E: PARTIAL gi over this quarter's Wih columns (t<900)
    if (t < 900) {
      int row = t >> 1, sub = t & 1;
      float acc0 = 0.f, acc1 = 0.f;
#define IHD(i2, A)                                                             \
  {                                                                            \
    int cq = c_lo + sub + 2 * (i2);                                            \
    if (cq <= c_hi) DOTC(b##i2, sRgh4[cq], A)                                  \
  }
      IHD(0, acc0) IHD(1, acc1) IHD(2, acc0) IHD(3, acc1) IHD(4, acc0)
      IHD(5, acc1) IHD(6, acc0) IHD(7, acc1) IHD(8, acc0) IHD(9, acc1)
#undef IHD
      float acc = acc0 + acc1;
      acc += __shfl_xor(acc, 1);
      if (!sub) stf_coh(&plGiP[456 * q + row], acc);
    }
    // ---- THE sync: post + poll (drains gh + gi coherent stores first)
    __syncthreads();
    if (t == 0) sti_coh(&myflags[q], i + 1);
    if (t < 4) {
      int spins = 0;
      while (ldi_coh(&myflags[t]) < i + 1 && ++spins < (1 << 20)) {
      }
    }
    BAR_LGKM();
    // ---- gather: gi = sum of 4 partials + bias (t<450); gh (t in [512,962))
    if (t < 450) {
      float g0 = ldf_coh(&plGiP[t]);
      float g1 = ldf_coh(&plGiP[456 + t]);
      float g2 = ldf_coh(&plGiP[912 + t]);
      float g3 = ldf_coh(&plGiP[1368 + t]);
      sGi[t] = g0 + g1 + g2 + g3 + sBih[t];
    } else if (t >= 512 && t < 962) {
      sGh[t - 512] = ldf_coh(&plGhP[t - 512]);
    }
    BAR_LGKM();

    // ---- Phase F (replicated): GRU update; q==0 stores out; stage next u
    if (t < 150) {
      float ir = sGi[t], iz = sGi[150 + t], in_ = sGi[300 + t];
      float hr = sGh[t], hz = sGh[150 + t], hn = sGh[300 + t];
      float rr = fast_sigmoid(ir + hr);
      float zz = fast_sigmoid(iz + hz);
      float nn = fast_tanh(in_ + rr * hn);
      float vold = sv_[t];
      float hv = nn + zz * (vold - nn);
      if (q == 0) out[i * 9600 + b * 150 + t] = hv;
      sv_[t] = hv;
      float hv1 = __shfl_down(hv, 1);
      if (!(t & 1)) svh[t >> 1] = packh2(hv, hv1);
    } else if (t >= 640 && t < 790) {
      int t2 = t - 640;
      sU[t2] = unext;
      float un = __shfl_down(unext, 1);
      if (!(t2 & 1)) sXd[t2 >> 1] = packh2(unext, un);
    }
    BAR_LGKM();  // store drains deferred to next step's pre-post syncthreads
  }
}

// ---------------------------------------------------------------------------
extern "C" void kernel_launch(void* const* d_in, const int* in_sizes, int n_in,
                              void* d_out, int out_size, void* d_ws,
                              size_t ws_size, hipStream_t stream) {
  const float* Up = (const float*)d_in[0];
  const float* Uq = (const float*)d_in[1];
  const float* Wp = (const float*)d_in[2];
  const float* Wq = (const float*)d_in[3];
  const float* Wv = (const float*)d_in[4];
  const float* Wg = (const float*)d_in[5];
  const float* V = (const float*)d_in[6];
  const float* v0 = (const float*)d_in[7];
  const float* Wih = (const float*)d_in[8];
  const float* Whh = (const float*)d_in[9];
  const float* bih = (const float*)d_in[10];
  const float* bhh = (const float*)d_in[11];

  char* ws = (char*)d_ws;
  __half* wsWuq = (__half*)(ws);            // 2,490,368 B
  __half* wsUqh = (__half*)(ws + 2490368);  // 2,490,368 B
  __half* wsMa = (__half*)(ws + 4980736);   //    91,200 B
  __half* wsWg = (__half*)(ws + 5071936);   //   364,800 B
  __half* wsWih = (__half*)(ws + 5436736);  //   547,200 B
  __half* wsWhh = (__half*)(ws + 5983936);  //   137,408 B
  int* wsFlags = (int*)(ws + 6121472);      //     4,096 B (64 clusters x 16)
  int* wsPayload = (int*)(ws + 6125568);    // 1,572,864 B (64 x 6,144 ints)

  (void)hipFuncSetAttribute((const void*)pq_main,
                            hipFuncAttributeMaxDynamicSharedMemorySize, 130112);

  prep_weights<<<2228, 256, 0, stream>>>(Wp, Wv, Wg, Wih, Whh, wsMa, wsWg,
                                         wsWih, wsWhh, wsFlags, wsPayload);
  prep_wuq<<<128, 256, 0, stream>>>(Uq, Wq, wsWuq, wsUqh);
  pq_main<<<256, 1024, 130112, stream>>>(Up, V, v0, bih, bhh, (const int*)wsWuq,
                                         wsUqh, (const int*)wsMa,
                                         (const int*)wsWg, (const int*)wsWih,
                                         (const int*)wsWhh, wsFlags, wsPayload,
                                         (float*)d_out);
}

// Round 13
// 1191.242 us; speedup vs baseline: 2.3364x; 2.3364x over previous
//
// Persistent clustered RNN for PQMatcher on gfx950.
// 256 blocks = 64 clusters (one per batch) x 4 blocks, 1024 threads each.
// ALL folded f16 weights in registers (a0-a9/b0-b9); Wuq/Uqh in LDS.
// R13 = R11 (best known-good, 1155us steady) + coherent-transaction
// reduction (the R7/R12 regressions + R4 evidence indicate the sync cost is
// COHERENT-POINT THROUGHPUT, not latency):
//  * plS laid out [4*l+q]  -> s-gather = 1x global_load_dwordx4 sc0 sc1
//    per thread (2048 -> 512 transactions per cluster-step).
//  * plGi laid out [4*row+q] -> gi-gather = 1x dwordx4 (7200 -> 1800).
//  * plGh gathered as pairs via dwordx2 (1800 -> 900).
//  Stores stay scalar agent-scope (scattered; cheap side). Reuse-safety
//  unchanged from R11 (2 syncs -> flag transitivity covers plS/plGh/plGi).
// 2 syncs/step: SYNC-1 (s-partials + gh, D_u overlapped), SYNC-2 (gi).
#include <hip/hip_runtime.h>
#include <hip/hip_fp16.h>

typedef _Float16 h2_t __attribute__((ext_vector_type(2)));

// LDS-only barrier: no vmcnt drain (use ONLY where no cross-wave VMEM dep).
#define BAR_LGKM() \
  asm volatile("s_waitcnt lgkmcnt(0)\n\ts_barrier" ::: "memory")

__device__ __forceinline__ float dot2f(int w, int x, float acc) {
#if __has_builtin(__builtin_amdgcn_fdot2)
  return __builtin_amdgcn_fdot2(__builtin_bit_cast(h2_t, w),
                                __builtin_bit_cast(h2_t, x), acc, false);
#else
  h2_t a = __builtin_bit_cast(h2_t, w);
  h2_t b = __builtin_bit_cast(h2_t, x);
  return acc + (float)a[0] * (float)b[0] + (float)a[1] * (float)b[1];
#endif
}

__device__ __forceinline__ float rcp_f(float x) {
#if __has_builtin(__builtin_amdgcn_rcpf)
  return __builtin_amdgcn_rcpf(x);
#else
  return 1.0f / x;
#endif
}

__device__ __forceinline__ float fast_tanh(float x) {
  float e = exp2f(x * 2.885390082f);
  return 1.0f - 2.0f * rcp_f(e + 1.0f);
}
__device__ __forceinline__ float fast_sigmoid(float x) {
  return rcp_f(1.0f + exp2f(x * -1.442695041f));
}
__device__ __forceinline__ int packh2(float a, float b) {
  h2_t h;
  h[0] = (_Float16)a;
  h[1] = (_Float16)b;
  return __builtin_bit_cast(int, h);
}

// Coherent (agent-scope, relaxed) scalar accessors: no cache-maintenance ops.
__device__ __forceinline__ int ldi_coh(const int* p) {
  return __hip_atomic_load((int*)p, __ATOMIC_RELAXED, __HIP_MEMORY_SCOPE_AGENT);
}
__device__ __forceinline__ void sti_coh(int* p, int v) {
  __hip_atomic_store(p, v, __ATOMIC_RELAXED, __HIP_MEMORY_SCOPE_AGENT);
}
__device__ __forceinline__ void stf_coh(float* p, float v) {
  __hip_atomic_store(p, v, __ATOMIC_RELAXED, __HIP_MEMORY_SCOPE_AGENT);
}
// Wide device-coherent loads (sc0 sc1 = bypass L1+L2, same semantics as the
// agent-scope atomic load, one transaction instead of 4/2).
__device__ __forceinline__ float4 ld16_coh(const void* p) {
  float4 v;
  asm volatile("global_load_dwordx4 %0, %1, off sc0 sc1\n\ts_waitcnt vmcnt(0)"
               : "=v"(v)
               : "v"(p)
               : "memory");
  return v;
}
__device__ __forceinline__ float2 ld8_coh(const void* p) {
  float2 v;
  asm volatile("global_load_dwordx2 %0, %1, off sc0 sc1\n\ts_waitcnt vmcnt(0)"
               : "=v"(v)
               : "v"(p)
               : "memory");
  return v;
}

#define DOTC(W, X, A)                                                          \
  {                                                                            \
    int4 _x = (X);                                                             \
    A = dot2f((W).x, _x.x, A);                                                 \
    A = dot2f((W).y, _x.y, A);                                                 \
    A = dot2f((W).z, _x.z, A);                                                 \
    A = dot2f((W).w, _x.w, A);                                                 \
  }

// ---------------------------------------------------------------------------
// Weight fold/transpose (unchanged layouts) + flag zeroing.
// ---------------------------------------------------------------------------
__global__ void prep_weights(const float* __restrict__ Wp,
                             const float* __restrict__ Wv,
                             const float* __restrict__ Wg,
                             const float* __restrict__ Wih,
                             const float* __restrict__ Whh,
                             __half* __restrict__ oMa, __half* __restrict__ oWg,
                             __half* __restrict__ oWih,
                             __half* __restrict__ oWhh, int* __restrict__ flags,
                             int* __restrict__ payload) {
  if (blockIdx.x == 0) {
    for (int j = threadIdx.x; j < 1024; j += 256) flags[j] = 0;
  }
  int idx = blockIdx.x * 256 + threadIdx.x;
  const int NMa = 150 * 304, NWg = 600 * 304, NWih = 900 * 304,
            NWhh = 452 * 152;
  if (idx < NMa) {
    int r = idx / 304, c = idx % 304;
    float v = 0.f;
    if (c < 150)
      v = Wp[r * 300 + c] + Wp[r * 300 + 150 + c];
    else if (c >= 152 && c < 302)
      v = Wv[r * 150 + (c - 152)];
    oMa[(c >> 3) * 1200 + r * 8 + (c & 7)] = __float2half(v);
    return;
  }
  idx -= NMa;
  if (idx < NWg) {
    int r = idx / 304, c = idx % 304;
    float v = 0.f;
    if (c < 150)
      v = Wg[r * 600 + c] + Wg[r * 600 + 150 + c];
    else if (c >= 152 && c < 302) {
      int d = c - 152;
      v = Wg[r * 600 + 300 + d] + Wg[r * 600 + 450 + d];
    }
    oWg[(c >> 3) * 4800 + r * 8 + (c & 7)] = __float2half(v);
    return;
  }
  idx -= NWg;
  if (idx < NWih) {
    int s = idx / 304, c = idx % 304;
    int r = s >> 1, off = (s & 1) * 300;
    float v = (c < 300) ? Wih[r * 600 + off + c] : 0.f;
    oWih[(c >> 3) * 7200 + s * 8 + (c & 7)] = __float2half(v);
    return;
  }
  idx -= NWih;
  if (idx < NWhh) {
    int r = idx / 152, c = idx % 152;
    float v = (r < 450 && c < 150) ? Whh[r * 150 + c] : 0.f;
    oWhh[(c >> 3) * 3616 + r * 8 + (c & 7)] = __float2half(v);
  }
}

// ---------------------------------------------------------------------------
// Prep 2: Wuq[b][l][h], Uqh[b][l][d]  (unchanged)
// ---------------------------------------------------------------------------
__global__ __launch_bounds__(256) void prep_wuq(const float* __restrict__ Uq,
                                                const float* __restrict__ Wq,
                                                __half* __restrict__ oWuq,
                                                __half* __restrict__ oUqh) {
  __shared__ float sUql[64 * 150];
  const int l = blockIdx.x, tid = threadIdx.x;
  for (int idx = tid; idx < 9600; idx += 256) sUql[idx] = Uq[l * 9600 + idx];
  __syncthreads();
  for (int idx = tid; idx < 64 * 152; idx += 256) {
    int bb = idx / 152, d = idx % 152;
    float v = (d < 150) ? sUql[bb * 150 + d] : 0.f;
    oUqh[(size_t)bb * 19456 + l * 152 + d] = __float2half(v);
  }
  if (tid < 152) {
    const int h = tid;
    if (h < 150) {
      float wq[150];
#pragma unroll
      for (int d = 0; d < 150; ++d)
        wq[d] = Wq[h * 300 + d] + Wq[h * 300 + 150 + d];
      for (int bb = 0; bb < 64; ++bb) {
        float acc = 0.f;
#pragma unroll
        for (int d = 0; d < 150; ++d) acc += wq[d] * sUql[bb * 150 + d];
        oWuq[(size_t)bb * 19456 + l * 152 + h] = __float2half(acc);
      }
    } else {
      for (int bb = 0; bb < 64; ++bb)
        oWuq[(size_t)bb * 19456 + l * 152 + h] = __float2half(0.f);
    }
  }
}

// ---------------------------------------------------------------------------
// post-flag + spin-wait (no sleep; 4 pollers/block only).
// ---------------------------------------------------------------------------
__device__ __forceinline__ void post_and_wait(int* f4, int q, int target) {
  __syncthreads();
  if (threadIdx.x == 0) sti_coh(&f4[q], target);
  if (threadIdx.x < 4) {
    int spins = 0;
    while (ldi_coh(&f4[threadIdx.x]) < target && ++spins < (1 << 20)) {
    }
  }
  BAR_LGKM();
}

// ---------------------------------------------------------------------------
__global__ __launch_bounds__(1024, 1) void pq_main(
    const float* __restrict__ Up, const float* __restrict__ V,
    const float* __restrict__ v0, const float* __restrict__ b_ih,
    const float* __restrict__ b_hh, const int* __restrict__ gWuq,
    const __half* __restrict__ gUqh, const int* __restrict__ gMa,
    const int* __restrict__ gWg, const int* __restrict__ gWih,
    const int* __restrict__ gWhh, int* __restrict__ flags,
    int* __restrict__ payload, float* __restrict__ out) {
  __shared__ __align__(16) float sTV[304];
  __shared__ __align__(16) float sV[152];
  __shared__ __align__(16) float sGh[456];
  __shared__ __align__(16) float sS[128];
  __shared__ __align__(16) float sSS[4];
  __shared__ __align__(16) float sC0[152];
  __shared__ __align__(16) float sU[152];
  __shared__ __align__(16) float sv_[152];
  __shared__ __align__(16) int sXd[152];
  __shared__ __align__(16) int svh[76];
  __shared__ __align__(16) int sRgh[304];
  __shared__ __align__(16) float sGi[456];
  __shared__ __align__(16) float sBih[456];
  __shared__ __align__(16) float sBhh[456];
  extern __shared__ __align__(16) int dynlds[];
  int* sWuq = dynlds;                       // 9728 ints (38,912 B)
  __half* sUqh = (__half*)(dynlds + 9728);  // padded: 4 x 2436 ints (38,976 B)

  const int t = threadIdx.x;
  const int c = blockIdx.x & 63;  // cluster == batch
  const int q = blockIdx.x >> 6;  // quarter within cluster
  const int b = c;

  int* myflags = flags + c * 16;
  int* pl = payload + c * 4096;
  float* plS = (float*)pl;            // s-partials: [4*l+q], 512 floats
  float* plGh = (float*)(pl + 512);   // gh [0,456)
  float* plGi = (float*)(pl + 1024);  // gi partials: [4*row+q], 1824 floats

  const int4* MaT4 = (const int4*)gMa;
  const int4* WgT4 = (const int4*)gWg;
  const int4* WihT4 = (const int4*)gWih;
  const int4* WhhT4 = (const int4*)gWhh;

  const int baseR = 113 * q - (q == 3 ? 1 : 0);  // 0,113,226,338
  const int cntR = (q < 2) ? 113 : 112;
  // Wih column-split chunk range for this quarter (packed-halves space)
  const int c_lo = (q == 0) ? 0 : (q == 1) ? 18 : (q == 2) ? 38 : 56;
  const int c_hi = (q == 0) ? 18 : (q == 1) ? 37 : (q == 2) ? 56 : 75;

  // ---- load ALL owned weight chunks into registers ----
  int4 a0, a1, a2, a3, a4, a5, a6, a7, a8, a9;
  int4 b0, b1, b2, b3, b4, b5, b6, b7, b8, b9;
  {
    const int4* p;
    int nr, sub, step, nch, row;
    if (t < 152) {  // Ma rows 38q+rl, 4 lanes/row
      p = MaT4; nr = 150; step = 4; nch = 38;
      sub = t & 3; row = 38 * q + (t >> 2);
      if (row > 149) row = 149;
    } else if (t < 378) {  // Whh rows baseR+rl, 2 lanes/row
      p = WhhT4; nr = 452; step = 2; nch = 19;
      int u2 = t - 152; sub = u2 & 1; row = baseR + (u2 >> 1);
    } else if (t >= 384 && t < 984) {  // Wg rows 150q+rl, 4 lanes/row
      p = WgT4; nr = 600; step = 4; nch = 38;
      int u2 = t - 384; sub = u2 & 3; row = 150 * q + (u2 >> 2);
    } else {
      p = MaT4; nr = 150; step = 4; nch = 38; sub = 0; row = 0;
    }
#define LDA(i)                                                                 \
  {                                                                            \
    int cc = sub + step * (i);                                                 \
    if (cc > nch - 1) cc = nch - 1;                                            \
    a##i = p[cc * nr + row];                                                   \
  }
    LDA(0) LDA(1) LDA(2) LDA(3) LDA(4) LDA(5) LDA(6) LDA(7) LDA(8) LDA(9)
#undef LDA
  }
  {
    // Wih COLUMN split: all 450 rows, chunks c_lo+sub+2k (k<10), 2 lanes/row
    int row = (t < 900) ? (t >> 1) : 0;
    int sub = (t < 900) ? (t & 1) : 0;
#define LDB(i)                                                                 \
  {                                                                            \
    int cq = c_lo + sub + 2 * (i);                                             \
    if (cq > c_hi) cq = c_hi;                                                  \
    int hf = (cq >= 38) ? 1 : 0;                                               \
    int cc = cq - 38 * hf;                                                     \
    b##i = WihT4[cc * 900 + 2 * row + hf];                                     \
  }
    LDB(0) LDB(1) LDB(2) LDB(3) LDB(4) LDB(5) LDB(6) LDB(7) LDB(8) LDB(9)
#undef LDB
  }

  // ---- LDS init: Wuq + Uqh (padded lq stride 2436 ints), state, biases ----
  for (int idx = t; idx < 9728; idx += 1024) sWuq[idx] = gWuq[b * 9728 + idx];
  {
    const int* gU2 = (const int*)(gUqh + (size_t)b * 19456);
    int* sU2 = (int*)sUqh;
    for (int idx = t; idx < 9728; idx += 1024) {
      int lq = idx / 2432, rem = idx - lq * 2432;
      sU2[lq * 2436 + rem] = gU2[idx];
    }
  }
  if (t < 150) {
    sV[t] = V[b * 150 + t];
    float v_ = v0[b * 150 + t];
    sv_[t] = v_;
    float vn = __shfl_down(v_, 1);
    if (!(t & 1)) svh[t >> 1] = packh2(v_, vn);
    float u_ = Up[b * 150 + t];
    sU[t] = u_;
    float un = __shfl_down(u_, 1);
    if (!(t & 1)) sXd[t >> 1] = packh2(u_, un);
  }
  for (int idx = t; idx < 450; idx += 1024) {
    sBih[idx] = b_ih[idx];
    sBhh[idx] = b_hh[idx];
  }
  if (t < 304) {
    sRgh[t] = 0;   // non-owned halves must stay zero (column split)
    sTV[t] = 0.f;  // unwritten tv slots
  }
  if (t == 0) {
    svh[75] = 0;
    sXd[75] = 0;
    sXd[151] = 0;
    sV[150] = 0.f;
    sV[151] = 0.f;
  }
  const int4* sXd4 = (const int4*)sXd;
  const int4* svh4 = (const int4*)svh;
  const int4* sRgh4 = (const int4*)sRgh;
  __syncthreads();

#pragma unroll 1
  for (int i = 0; i < 128; ++i) {
    float accD0 = 0.f, accD1 = 0.f;  // D_u/D_c accumulators (waves 6-15)
    float unext = 0.f;
    if (t >= 640 && t < 790) {
      int ii = (i < 127) ? (i + 1) : 127;
      unext = Up[ii * 9600 + b * 150 + (t - 640)];
    }

    // ---- Phase 1: tpre quarter -> LOCAL sTV (t<152) || gh -> payload
    if (t < 152) {
      int rl = t >> 2, sub = t & 3;
      float acc0 = 0.f, acc1 = 0.f;
#define MAD(i2, A)                                                             \
  {                                                                            \
    int cc = sub + 4 * (i2);                                                   \
    if (cc < 38) {                                                             \
      int4 x = (cc < 19) ? sXd4[cc] : svh4[cc - 19];                           \
      DOTC(a##i2, x, A)                                                        \
    }                                                                          \
  }
      MAD(0, acc0) MAD(1, acc1) MAD(2, acc0) MAD(3, acc1) MAD(4, acc0)
      MAD(5, acc1) MAD(6, acc0) MAD(7, acc1) MAD(8, acc0) MAD(9, acc1)
#undef MAD
      float acc = acc0 + acc1;
      acc += __shfl_xor(acc, 1);
      acc += __shfl_xor(acc, 2);
      float accN = __shfl_down(acc, 4);  // tpre of rl+1 (same wave: rl even)
      if (sub == 0 && !(rl & 1)) {
        int w = 19 * q + (rl >> 1);
        int h = 38 * q + rl;
        float4 tv;
        tv.x = acc;
        tv.y = accN;
        tv.z = sV[h];
        tv.w = sV[h + 1];
        ((float4*)sTV)[w] = tv;
      }
    } else if (t < 378) {
      int u2 = t - 152;
      int rl = u2 >> 1, sub = u2 & 1;
      int r = baseR + rl;
      float acc0 = 0.f, acc1 = 0.f;
#define HHD(i2, A)                                                             \
  {                                                                            \
    int cc = sub + 2 * (i2);                                                   \
    if (cc < 19) DOTC(a##i2, svh4[cc], A)                                      \
  }
      HHD(0, acc0) HHD(1, acc1) HHD(2, acc0) HHD(3, acc1) HHD(4, acc0)
      HHD(5, acc1) HHD(6, acc0) HHD(7, acc1) HHD(8, acc0) HHD(9, acc1)
#undef HHD
      float acc = acc0 + acc1;
      acc += __shfl_xor(acc, 1);
      if (sub == 0 && rl < cntR) stf_coh(&plGh[r], acc + sBhh[r]);
    }
    BAR_LGKM();  // gh posts drain deferred to SYNC-1 pre-post barrier

    // ---- Phase B' (quarter): s_l^q over OWN 19 w-slots; post to payload
    {
      const int l = t >> 3, sub = t & 7;
      const int base = l * 76;
      float acc = 0.f;
#pragma unroll
      for (int k = 0; k < 3; ++k) {
        int wl = sub + 8 * k;
        if (wl < 19) {
          int w = 19 * q + wl;
          int qq = sWuq[base + w];
          float4 tv = ((const float4*)sTV)[w];
          h2_t hq = __builtin_bit_cast(h2_t, qq);
          float x0 = (float)hq[0] + tv.x;
          float x1 = (float)hq[1] + tv.y;
          acc += fast_tanh(x0) * tv.z;
          acc += fast_tanh(x1) * tv.w;
        }
      }
      acc += __shfl_xor(acc, 1);
      acc += __shfl_xor(acc, 2);
      acc += __shfl_xor(acc, 4);
      if (sub == 0) stf_coh(&plS[4 * l + q], acc);
    }
    // ---- SYNC-1 with D_u overlap: post -> D_u (waves 6-15) while
    //      threads 0-3 (wave 0, not D-threads) poll the flags.
    __syncthreads();
    if (t == 0) sti_coh(&myflags[q], i + 1);
    if (t >= 384 && t < 984) {
      int sub = (t - 384) & 3;
#define WGU(i2, A)                                                             \
  {                                                                            \
    int cc = sub + 4 * (i2);                                                   \
    if (cc < 19) DOTC(a##i2, sXd4[cc], A)                                      \
  }
      WGU(0, accD0) WGU(1, accD1) WGU(2, accD0) WGU(3, accD1) WGU(4, accD0)
#undef WGU
    }
    if (t < 4) {
      int spins = 0;
      while (ldi_coh(&myflags[t]) < i + 1 && ++spins < (1 << 20)) {
      }
    }
    BAR_LGKM();
    // ---- gather s: ONE dwordx4 per thread (contiguous partials), exp;
    //      per-wave e-sums -> sSS; gh gathered as dwordx2 pairs
    if (t < 128) {
      float4 sp = ld16_coh(&plS[4 * t]);
      float s = sp.x + sp.y + sp.z + sp.w;
      float e = exp2f(s * 1.442695041f);
      sS[t] = e;
      float es = e;
#pragma unroll
      for (int o = 1; o < 64; o <<= 1) es += __shfl_xor(es, o);
      if (t == 0) sSS[0] = es;
      if (t == 64) sSS[1] = es;
    } else if (t >= 128 && t < 353) {
      int p2 = t - 128;
      float2 g2 = ld8_coh(&plGh[2 * p2]);
      sGh[2 * p2] = g2.x;
      sGh[2 * p2 + 1] = g2.y;
    }
    BAR_LGKM();

    // ---- Phase C (replicated): c0 via in-wave lq reduce; no CS phase.
    if (t < 600) {
      const int d = t >> 2, lq = t & 3;
      const __half* src = sUqh + lq * 4872 + d;
      const float* a = sS + lq * 32;
      float acc = 0.f;
#pragma unroll
      for (int j = 0; j < 32; ++j) {
        acc += a[j] * __half2float(src[j * 152]);
      }
      acc += __shfl_xor(acc, 1);
      acc += __shfl_xor(acc, 2);  // all 4 lanes now hold full c0_raw[d]
      float inv = rcp_f(sSS[0] + sSS[1]);
      float c0 = acc * inv;
      float cn = __shfl_down(c0, 4);  // c0[d+1]
      if (lq == 0) {
        sC0[d] = c0;
        if (!(d & 1)) sXd[76 + (d >> 1)] = packh2(c0, cn);
      }
    }
    BAR_LGKM();

    // ---- Phase D_c: finish rg with c0 columns (chunks 19-37), local write
    if (t >= 384 && t < 984) {
      int u2 = t - 384;
      int rl = u2 >> 2, sub = u2 & 3;
      int j = 150 * q + rl;
#define WGC(i2, A)                                                             \
  {                                                                            \
    int cc = sub + 4 * (i2);                                                   \
    if (cc >= 19 && cc < 38) DOTC(a##i2, sXd4[cc], A)                          \
  }
      WGC(4, accD1) WGC(5, accD0) WGC(6, accD1) WGC(7, accD0) WGC(8, accD1)
      WGC(9, accD0)
#undef WGC
      float acc = accD0 + accD1;
      acc += __shfl_xor(acc, 1);
      acc += __shfl_xor(acc, 2);
      if (sub == 0) {
        float rb;
        if (j < 150)
          rb = sU[j];
        else if (j < 300)
          rb = sU[j - 150];
        else if (j < 450)
          rb = sC0[j - 300];
        else
          rb = sC0[j - 450];
        float rg = rb * fast_sigmoid(acc);
        ((__half*)sRgh)[(j < 300) ? j : (j + 4)] = __float2half(rg);
      }
    }
    BAR_LGKM();

    // ---- Phase E: PARTIAL gi over this quarter's Wih columns (t<900)
    if (t < 900) {
      int row = t >> 1, sub = t & 1;
      float acc0 = 0.f, acc1 = 0.f;
#define IHD(i2, A)                                                             \
  {                                                                            \
    int cq = c_lo + sub + 2 * (i2);                                            \
    if (cq <= c_hi) DOTC(b##i2, sRgh4[cq], A)                                  \
  }
      IHD(0, acc0) IHD(1, acc1) IHD(2, acc0) IHD(3, acc1) IHD(4, acc0)
      IHD(5, acc1) IHD(6, acc0) IHD(7, acc1) IHD(8, acc0) IHD(9, acc1)
#undef IHD
      float acc = acc0 + acc1;
      acc += __shfl_xor(acc, 1);
      if (!sub) stf_coh(&plGi[4 * row + q], acc);
    }
    // ---- SYNC-2: gather gi = ONE dwordx4 per thread + bias
    post_and_wait(myflags + 4, q, i + 1);
    if (t < 450) {
      float4 gp = ld16_coh(&plGi[4 * t]);
      sGi[t] = gp.x + gp.y + gp.z + gp.w + sBih[t];
    }
    BAR_LGKM();

    // ---- Phase F (replicated): GRU update; q==0 stores out; stage next u
    if (t < 150) {
      float ir = sGi[t], iz = sGi[150 + t], in_ = sGi[300 + t];
      float hr = sGh[t], hz = sGh[150 + t], hn = sGh[300 + t];
      float rr = fast_sigmoid(ir + hr);
      float zz = fast_sigmoid(iz + hz);
      float nn = fast_tanh(in_ + rr * hn);
      float vold = sv_[t];
      float hv = nn + zz * (vold - nn);
      if (q == 0) out[i * 9600 + b * 150 + t] = hv;
      sv_[t] = hv;
      float hv1 = __shfl_down(hv, 1);
      if (!(t & 1)) svh[t >> 1] = packh2(hv, hv1);
    } else if (t >= 640 && t < 790) {
      int t2 = t - 640;
      sU[t2] = unext;
      float un = __shfl_down(unext, 1);
      if (!(t2 & 1)) sXd[t2 >> 1] = packh2(unext, un);
    }
    BAR_LGKM();  // out-store drain deferred to next SYNC-1 pre-post
  }
}

// ---------------------------------------------------------------------------
extern "C" void kernel_launch(void* const* d_in, const int* in_sizes, int n_in,
                              void* d_out, int out_size, void* d_ws,
                              size_t ws_size, hipStream_t stream) {
  const float* Up = (const float*)d_in[0];
  const float* Uq = (const float*)d_in[1];
  const float* Wp = (const float*)d_in[2];
  const float* Wq = (const float*)d_in[3];
  const float* Wv = (const float*)d_in[4];
  const float* Wg = (const float*)d_in[5];
  const float* V = (const float*)d_in[6];
  const float* v0 = (const float*)d_in[7];
  const float* Wih = (const float*)d_in[8];
  const float* Whh = (const float*)d_in[9];
  const float* bih = (const float*)d_in[10];
  const float* bhh = (const float*)d_in[11];

  char* ws = (char*)d_ws;
  __half* wsWuq = (__half*)(ws);            // 2,490,368 B
  __half* wsUqh = (__half*)(ws + 2490368);  // 2,490,368 B
  __half* wsMa = (__half*)(ws + 4980736);   //    91,200 B
  __half* wsWg = (__half*)(ws + 5071936);   //   364,800 B
  __half* wsWih = (__half*)(ws + 5436736);  //   547,200 B
  __half* wsWhh = (__half*)(ws + 5983936);  //   137,408 B
  int* wsFlags = (int*)(ws + 6121472);      //     4,096 B (64 clusters x 16)
  int* wsPayload = (int*)(ws + 6125568);    // 1,048,576 B (64 x 16,384)

  (void)hipFuncSetAttribute((const void*)pq_main,
                            hipFuncAttributeMaxDynamicSharedMemorySize, 77888);

  prep_weights<<<2228, 256, 0, stream>>>(Wp, Wv, Wg, Wih, Whh, wsMa, wsWg,
                                         wsWih, wsWhh, wsFlags, wsPayload);
  prep_wuq<<<128, 256, 0, stream>>>(Uq, Wq, wsWuq, wsUqh);
  pq_main<<<256, 1024, 77888, stream>>>(Up, V, v0, bih, bhh, (const int*)wsWuq,
                                        wsUqh, (const int*)wsMa,
                                        (const int*)wsWg, (const int*)wsWih,
                                        (const int*)wsWhh, wsFlags, wsPayload,
                                        (float*)d_out);
}